// Round 12
// baseline (370.008 us; speedup 1.0000x reference)
//
#include <hip/hip_runtime.h>
#include <cstdint>

// MTNN: static MLP + dyn proj + biRNN(relu) + routed per-trial dot.
// B=512,T=200,SI=100,DI=68,HS=256,HD=128,D=512,K=1. fp32 in, fp32 out.
// R20 (passed, 244.5us): persistent weight-hoisted k_dxw. k_scan 68us leads;
// its step is DS-broadcast + barrier bound (~32KB LDS reads/step floor).
// R21: FUSE dxw+scan as producer/consumer in ONE 256-block kernel (1
// block/CU by capacity: launch_bounds(256,1), VGPR<=512, LDS 39KB).
//  - blocks 64..255: R20 dxw, tiles reordered T-MAJOR (tile = 64 b x 1 t),
//    slabs from both ends (t=0,199,1,198,...) so fwd+bwd scans both feed.
//    Per tile: syncthreads (drains stores) + atomic RELEASE flags[t]+=1.
//  - blocks 0..63: 4-wave scan (R16 structure, per-wave acc slices). Gate
//    every 4 steps: lane0 spins on flags[t]==8 (ACQUIRE, agent scope ->
//    L2-inv fixes cross-XCD staleness), raw s_barrier releases block.
//    Bounded spin (no hang). During ramp, consumers also run k_static
//    (8 b's each, LDS overlaid) -> separate k_static launch deleted.
// Scan consumes ~443ns/dir-step < production ~700-800ns/dir-slab ->
// producer-bound: fused wall ~= T_dxw(192 blocks) + eps.
constexpr int B = 512, T = 200, SI = 100, DI = 68, HS = 256, HD = 128, D = 512;
constexpr int BT = B * T;     // 102400
constexpr int NTILE = BT / 64;  // 1600 (t-major: 200 slabs x 8 subtiles)
constexpr int NCONS = 64, NPROD = 192;

typedef __attribute__((ext_vector_type(8))) short short8;       // 8 bf16
typedef __attribute__((ext_vector_type(4))) float floatx4;      // MFMA C/D
typedef _Float16 half8 __attribute__((ext_vector_type(8)));     // 8 fp16
typedef _Float16 half2t __attribute__((ext_vector_type(2)));    // fp16 pair
typedef unsigned int uint2v __attribute__((ext_vector_type(2)));
typedef unsigned int uint4v __attribute__((ext_vector_type(4)));

#define DEV __device__ __forceinline__

DEV unsigned short f2bf(float f) {
    unsigned int x = __builtin_bit_cast(unsigned int, f);
    x += 0x7fffu + ((x >> 16) & 1u);   // RNE
    return (unsigned short)(x >> 16);
}
DEV unsigned int pkbf(float a, float b) {
    return (unsigned int)f2bf(a) | ((unsigned int)f2bf(b) << 16);
}
DEV unsigned short f2h(float f) {
    return __builtin_bit_cast(unsigned short, (_Float16)f);
}
DEV half2t u2h2(unsigned int u) { return __builtin_bit_cast(half2t, u); }
DEV unsigned int pkh(float a, float b) {
    return __builtin_bit_cast(unsigned int, __builtin_amdgcn_cvt_pkrtz(a, b));
}
#if __has_builtin(__builtin_amdgcn_permlane32_swap) && __has_builtin(__builtin_amdgcn_permlane16_swap)
DEV void pl32swap(unsigned int& a, unsigned int& b) {
    uint2v r = __builtin_amdgcn_permlane32_swap(a, b, false, false);
    a = r[0]; b = r[1];
}
DEV void pl16swap(unsigned int& a, unsigned int& b) {
    uint2v r = __builtin_amdgcn_permlane16_swap(a, b, false, false);
    a = r[0]; b = r[1];
}
#else
DEV void pl32swap(unsigned int& a, unsigned int& b) {
    unsigned int na, nb;
    asm("v_mov_b32 %0, %2\n\t"
        "v_mov_b32 %1, %3\n\t"
        "v_permlane32_swap_b32 %0, %1"
        : "=&v"(na), "=&v"(nb) : "v"(a), "v"(b));
    a = na; b = nb;
}
DEV void pl16swap(unsigned int& a, unsigned int& b) {
    unsigned int na, nb;
    asm("v_mov_b32 %0, %2\n\t"
        "v_mov_b32 %1, %3\n\t"
        "v_permlane16_swap_b32 %0, %1"
        : "=&v"(na), "=&v"(nb) : "v"(a), "v"(b));
    a = na; b = nb;
}
#endif

// ---------------- K0: one-time weight conversion + flag zeroing -------------
__global__ __launch_bounds__(256) void k_prep(
    const float* __restrict__ wdyn,
    const float* __restrict__ wihf, const float* __restrict__ wihb,
    const float* __restrict__ whhf, const float* __restrict__ whhb,
    const float* __restrict__ bihf, const float* __restrict__ bhhf,
    const float* __restrict__ bihb, const float* __restrict__ bhhb,
    unsigned short* __restrict__ wdyn_bf, unsigned short* __restrict__ wih_bf,
    unsigned short* __restrict__ whh_h, float* __restrict__ bsum,
    int* __restrict__ flags)
{
    int gid = blockIdx.x * 256 + threadIdx.x, gs = gridDim.x * 256;
    for (int i = gid; i < HD * 96; i += gs) {
        int r = i / 96, c = i - r * 96;
        wdyn_bf[i] = (c < DI) ? f2bf(wdyn[r * DI + c]) : 0;
    }
    for (int i = gid; i < 2 * HD * HD; i += gs) {
        const float* src = (i < HD * HD) ? wihf : wihb;
        wih_bf[i] = f2bf(src[i & (HD * HD - 1)]);
    }
    for (int i = gid; i < 2 * HD * HD; i += gs) {
        const float* src = (i < HD * HD) ? whhf : whhb;
        whh_h[i] = f2h(src[i & (HD * HD - 1)]);
    }
    for (int i = gid; i < 2 * HD; i += gs) {
        int z = i >> 7, n = i & (HD - 1);
        bsum[i] = z ? (bihb[n] + bhhb[n]) : (bihf[n] + bhhf[n]);
    }
    for (int i = gid; i < 256; i += gs) flags[i] = 0;
}

// ---------------- K1: fused producer (dxw) / consumer (static + scan) -------
__global__ __launch_bounds__(256, 1) void k_fused(
    const float* __restrict__ xd,
    const unsigned short* __restrict__ wdyn_bf, const float* __restrict__ bdyn,
    const unsigned short* __restrict__ wih_bf, const float* __restrict__ bsum,
    unsigned short* __restrict__ xw, const unsigned short* __restrict__ whh_h,
    const int* __restrict__ norder, const float* __restrict__ nw,
    float* __restrict__ accf, float* __restrict__ accb,
    int* __restrict__ flags,
    const float* __restrict__ xs_g, const float* __restrict__ w1,
    const float* __restrict__ b1, const float* __restrict__ w2,
    const float* __restrict__ b2, const float* __restrict__ nb,
    float* __restrict__ statd)
{
    __shared__ __align__(16) unsigned short xb[64][104];   // producer x stage
    __shared__ __align__(16) unsigned short dl[64][136];   // producer d stage
    __shared__ __align__(16) uint4v hxch[2][4][64];        // consumer (8KB)

    int tid = threadIdx.x;
    int lane = tid & 63, wv = tid >> 6, ln = lane & 15, q = lane >> 4;

    if (blockIdx.x >= NCONS) {
        // =================== PRODUCER (R20 dxw, t-major tiles) ==============
        int p = blockIdx.x - NCONS;
        short8 wdf[8][3];
        #pragma unroll
        for (int j = 0; j < 8; ++j)
            #pragma unroll
            for (int c = 0; c < 3; ++c)
                wdf[j][c] = *(const short8*)(wdyn_bf + (size_t)(j * 16 + ln) * 96 + c * 32 + q * 8);
        short8 wif[2][8][4];
        #pragma unroll
        for (int z = 0; z < 2; ++z)
            #pragma unroll
            for (int j = 0; j < 8; ++j)
                #pragma unroll
                for (int c = 0; c < 4; ++c)
                    wif[z][j][c] = *(const short8*)(wih_bf + (size_t)z * HD * HD +
                        (size_t)(j * 16 + ln) * HD + c * 32 + q * 8);
        for (int i = tid; i < 64 * 104 / 8; i += 256)
            ((uint4v*)xb)[i] = uint4v{0u, 0u, 0u, 0u};

        for (int m = p; m < NTILE; m += NPROD) {
            int slab = m >> 3, sub = m & 7;
            int t = (slab & 1) ? (T - 1 - (slab >> 1)) : (slab >> 1);
            int b0 = sub * 64;
            __syncthreads();   // xb free (prev P2 consumed it)
            for (int i = tid; i < 64 * 17; i += 256) {
                int r = i / 17, c2 = i - r * 17;
                float4 v = *(const float4*)(xd + ((size_t)(b0 + r) * T + t) * DI + c2 * 4);
                uint2 pk;
                pk.x = pkbf(v.x, v.y);
                pk.y = pkbf(v.z, v.w);
                *(uint2*)&xb[r][c2 * 4] = pk;
            }
            __syncthreads();
            // P2: d = relu(x Wdyn^T + b)
            short8 xf[3];
            #pragma unroll
            for (int c = 0; c < 3; ++c)
                xf[c] = *(const short8*)&xb[wv * 16 + ln][c * 32 + q * 8];
            #pragma unroll
            for (int j = 0; j < 8; ++j) {
                floatx4 a = {0.f, 0.f, 0.f, 0.f};
                #pragma unroll
                for (int c = 0; c < 3; ++c)
                    a = __builtin_amdgcn_mfma_f32_16x16x32_bf16(wdf[j][c], xf[c], a, 0, 0, 0);
                float4 bd4 = *(const float4*)(bdyn + j * 16 + q * 4);
                uint2 pk;
                pk.x = pkbf(fmaxf(a[0] + bd4.x, 0.f), fmaxf(a[1] + bd4.y, 0.f));
                pk.y = pkbf(fmaxf(a[2] + bd4.z, 0.f), fmaxf(a[3] + bd4.w, 0.f));
                *(uint2*)&dl[wv * 16 + ln][j * 16 + q * 4] = pk;
            }
            __syncthreads();
            // P3: xw = d Wih^T + bsum, both dirs
            short8 df[4];
            #pragma unroll
            for (int c = 0; c < 4; ++c)
                df[c] = *(const short8*)&dl[wv * 16 + ln][c * 32 + q * 8];
            int brow = b0 + wv * 16 + ln;
            #pragma unroll
            for (int z = 0; z < 2; ++z) {
                unsigned short* outp = xw + (size_t)z * BT * HD;
                #pragma unroll
                for (int j = 0; j < 8; ++j) {
                    floatx4 a = {0.f, 0.f, 0.f, 0.f};
                    #pragma unroll
                    for (int c = 0; c < 4; ++c)
                        a = __builtin_amdgcn_mfma_f32_16x16x32_bf16(wif[z][j][c], df[c], a, 0, 0, 0);
                    float4 b4 = *(const float4*)(bsum + z * HD + j * 16 + q * 4);
                    uint2 hp;
                    hp.x = (unsigned int)f2h(a[0] + b4.x) | ((unsigned int)f2h(a[1] + b4.y) << 16);
                    hp.y = (unsigned int)f2h(a[2] + b4.z) | ((unsigned int)f2h(a[3] + b4.w) << 16);
                    *(uint2*)(outp + ((size_t)brow * T + t) * HD + j * 16 + q * 4) = hp;
                }
            }
            __syncthreads();   // drains vmcnt: all xw stores complete (in L2)
            if (tid == 0)
                __hip_atomic_fetch_add(&flags[t], 1, __ATOMIC_RELEASE,
                                       __HIP_MEMORY_SCOPE_AGENT);
        }
        return;
    }

    // ===================== CONSUMER (static phase + scan) ===================
    int g = blockIdx.x;                 // 0..63
    int dirv = g >> 5, b0 = (g & 31) * 16;

    // ---- k_static for b = g*8 .. g*8+7 (LDS overlaid on hxch, during ramp)
    {
        float* sxs = (float*)hxch;          // 100 floats (pad 104)
        float* ss1 = sxs + 104;             // 256
        float* sred = ss1 + 256;            // 256  (total 2.4KB < 8KB)
        for (int bb = g * 8; bb < g * 8 + 8; ++bb) {
            if (tid < SI) sxs[tid] = xs_g[bb * SI + tid];
            __syncthreads();
            float a = b1[tid];
            const float4* wr = (const float4*)(w1 + tid * SI);
            const float4* xp4 = (const float4*)sxs;
            #pragma unroll
            for (int i = 0; i < SI / 4; ++i) {
                float4 ww = wr[i]; float4 xx = xp4[i];
                a += xx.x * ww.x + xx.y * ww.y + xx.z * ww.z + xx.w * ww.w;
            }
            ss1[tid] = fmaxf(a, 0.f);
            __syncthreads();
            float a2 = b2[tid];
            const float4* w2p = (const float4*)(w2 + tid * HS);
            const float4* s1p = (const float4*)ss1;
            #pragma unroll 8
            for (int i = 0; i < HS / 4; ++i) {
                float4 ww = w2p[i]; float4 s = s1p[i];
                a2 += s.x * ww.x + s.y * ww.y + s.z * ww.z + s.w * ww.w;
            }
            float sv = fmaxf(a2, 0.f);
            int n = norder[bb];
            sred[tid] = sv * nw[(size_t)n * D + tid];
            __syncthreads();
            for (int s = 128; s > 0; s >>= 1) {
                if (tid < s) sred[tid] += sred[tid + s];
                __syncthreads();
            }
            if (tid == 0) statd[bb] = sred[0] + nb[n];
            __syncthreads();
        }
    }

    // ---- scan (R16 4-wave structure, per-wave acc slices, flag gates)
    const unsigned short* whh = whh_h + (size_t)dirv * HD * HD;
    float* accp = (dirv ? accb : accf) + (size_t)wv * BT + (size_t)(b0 + ln) * T;
    int segoff = dirv ? (HS + HD) : HS;
    int j0 = 2 * wv;

    half8 wfr[2][4];
    #pragma unroll
    for (int jj = 0; jj < 2; ++jj)
        #pragma unroll
        for (int c = 0; c < 4; ++c)
            wfr[jj][c] = *(const half8*)(whh + (size_t)((j0 + jj) * 16 + ln) * HD + c * 32 + q * 8);

    int nrow = norder[b0 + ln];
    float4 wnl[2];
    #pragma unroll
    for (int jj = 0; jj < 2; ++jj)
        wnl[jj] = *(const float4*)(nw + (size_t)nrow * D + segoff + (j0 + jj) * 16 + q * 4);

    half8 hf[4];
    uint4v zz = {0u, 0u, 0u, 0u};
    #pragma unroll
    for (int c = 0; c < 4; ++c) hf[c] = __builtin_bit_cast(half8, zz);

    const unsigned short* xp = xw + ((size_t)dirv * BT + (size_t)(b0 + ln) * T) * HD;
    int tstart = dirv ? (T - 1) : 0, dt = dirv ? -1 : 1;

    auto gate = [&](int idx) {   // ensure flags for t(idx..idx+3) == 8
        if (tid == 0) {
            #pragma unroll 1
            for (int k = 0; k < 4; ++k) {
                int ii = idx + k;
                if (ii >= T) break;
                int t = tstart + dt * ii;
                // bounded spin (no-hang safety); ACQUIRE gives L1/L2 inv
                for (int it = 0; it < (1 << 20); ++it) {
                    if (__hip_atomic_load(&flags[t], __ATOMIC_ACQUIRE,
                                          __HIP_MEMORY_SCOPE_AGENT) >= 8) break;
                    __builtin_amdgcn_s_sleep(8);
                }
            }
        }
        __builtin_amdgcn_sched_barrier(0);
        __builtin_amdgcn_s_barrier();
        __builtin_amdgcn_sched_barrier(0);
    };

    uint2 x0[2], x1[2], x2[2], x3[2];
    auto ld = [&](uint2 (&xc)[2], int idx) {
        const unsigned short* pp = xp + (size_t)(tstart + dt * idx) * HD;
        #pragma unroll
        for (int jj = 0; jj < 2; ++jj)
            xc[jj] = *(const uint2*)(pp + (j0 + jj) * 16 + q * 4);
    };
    auto step = [&](uint2 (&xc)[2], int idx) {
        int t = tstart + dt * idx;
        int par = idx & 1;
        floatx4 a[2];
        #pragma unroll
        for (int jj = 0; jj < 2; ++jj) {
            half2t lo = u2h2(xc[jj].x), hi = u2h2(xc[jj].y);
            a[jj] = floatx4{(float)lo[0], (float)lo[1], (float)hi[0], (float)hi[1]};
        }
        #pragma unroll
        for (int cc = 0; cc < 4; ++cc)
            #pragma unroll
            for (int jj = 0; jj < 2; ++jj)
                a[jj] = __builtin_amdgcn_mfma_f32_16x16x32_f16(wfr[jj][cc], hf[cc], a[jj], 0, 0, 0);
        uint2 hp[2];
        float pdot = 0.f;
        #pragma unroll
        for (int jj = 0; jj < 2; ++jj) {
            float r0 = fmaxf(a[jj][0], 0.f), r1 = fmaxf(a[jj][1], 0.f);
            float r2 = fmaxf(a[jj][2], 0.f), r3 = fmaxf(a[jj][3], 0.f);
            hp[jj].x = pkh(r0, r1);
            hp[jj].y = pkh(r2, r3);
            float4 wn4 = wnl[jj];
            pdot += r0 * wn4.x + r1 * wn4.y + r2 * wn4.z + r3 * wn4.w;
        }
        unsigned int ax = hp[0].x, bx = hp[1].x;
        pl32swap(ax, bx); pl16swap(ax, bx);
        unsigned int ay = hp[0].y, by = hp[1].y;
        pl32swap(ay, by); pl16swap(ay, by);
        hxch[par][wv][lane] = uint4v{ax, ay, bx, by};
        unsigned int pa = __builtin_bit_cast(unsigned int, pdot), pb = pa;
        pl32swap(pa, pb);
        float ps = __builtin_bit_cast(float, pa) + __builtin_bit_cast(float, pb);
        unsigned int pc = __builtin_bit_cast(unsigned int, ps), pd = pc;
        pl16swap(pc, pd);
        float ptot = __builtin_bit_cast(float, pc) + __builtin_bit_cast(float, pd);
        if (lane < 16) accp[t] = ptot;
        asm volatile("s_waitcnt lgkmcnt(0)" ::: "memory");
        __builtin_amdgcn_sched_barrier(0);
        __builtin_amdgcn_s_barrier();
        __builtin_amdgcn_sched_barrier(0);
        #pragma unroll
        for (int c = 0; c < 4; ++c)
            hf[c] = __builtin_bit_cast(half8, hxch[par][c][lane]);
    };

    gate(0);
    ld(x0, 0); ld(x1, 1); ld(x2, 2); ld(x3, 3);
    for (int c = 0; c < T / 4 - 1; ++c) {
        int i0 = c * 4;
        gate(i0 + 4);
        step(x0, i0);     ld(x0, i0 + 4);
        step(x1, i0 + 1); ld(x1, i0 + 5);
        step(x2, i0 + 2); ld(x2, i0 + 6);
        step(x3, i0 + 3); ld(x3, i0 + 7);
    }
    step(x0, T - 4);
    step(x1, T - 3);
    step(x2, T - 2);
    step(x3, T - 1);
}

// ---------------- K2: out = relu(statd + sum of 4+4 partials) -> FP32 -------
__global__ __launch_bounds__(256) void k_final(
    const float* __restrict__ statd, const float* __restrict__ accf,
    const float* __restrict__ accb, float* __restrict__ out)
{
    int idx = blockIdx.x * 256 + threadIdx.x;
    if (idx < BT) {
        int b = idx / T;
        float s = statd[b];
        #pragma unroll
        for (int w = 0; w < 4; ++w)
            s += accf[(size_t)w * BT + idx] + accb[(size_t)w * BT + idx];
        out[idx] = fmaxf(s, 0.f);
    }
}

extern "C" void kernel_launch(void* const* d_in, const int* in_sizes, int n_in,
                              void* d_out, int out_size, void* d_ws, size_t ws_size,
                              hipStream_t stream)
{
    const float* x_static  = (const float*)d_in[0];
    const float* x_dynamic = (const float*)d_in[1];
    const int*   norder    = (const int*)d_in[2];
    const float* w_s1   = (const float*)d_in[3];
    const float* b_s1   = (const float*)d_in[4];
    const float* w_s2   = (const float*)d_in[5];
    const float* b_s2   = (const float*)d_in[6];
    const float* w_dyn  = (const float*)d_in[7];
    const float* b_dyn  = (const float*)d_in[8];
    const float* w_ih_f = (const float*)d_in[9];
    const float* w_hh_f = (const float*)d_in[10];
    const float* b_ih_f = (const float*)d_in[11];
    const float* b_hh_f = (const float*)d_in[12];
    const float* w_ih_b = (const float*)d_in[13];
    const float* w_hh_b = (const float*)d_in[14];
    const float* b_ih_b = (const float*)d_in[15];
    const float* b_hh_b = (const float*)d_in[16];
    const float* nw     = (const float*)d_in[17];
    const float* nb     = (const float*)d_in[18];
    float* out = (float*)d_out;

    // ws: statd 2KB | accf 4*BT*4 | accb 4*BT*4 | xw 52.4MB | wts | flags
    char* ws = (char*)d_ws;
    float* statd = (float*)ws;
    float* accf  = (float*)(ws + 2048);
    float* accb  = (float*)(ws + 2048 + (size_t)4 * BT * 4);
    unsigned short* xw = (unsigned short*)(ws + 2048 + (size_t)8 * BT * 4);
    size_t xw_bytes = (size_t)2 * BT * HD * 2;   // 52.4 MB
    unsigned short* wdyn_bf = (unsigned short*)(ws + 2048 + (size_t)8 * BT * 4 + xw_bytes);
    unsigned short* wih_bf  = wdyn_bf + HD * 96;
    unsigned short* whh_h   = wih_bf + 2 * HD * HD;
    float* bsum  = (float*)(whh_h + 2 * HD * HD);
    int*   flags = (int*)(bsum + 2 * HD);

    hipLaunchKernelGGL(k_prep, dim3(64), dim3(256), 0, stream,
                       w_dyn, w_ih_f, w_ih_b, w_hh_f, w_hh_b,
                       b_ih_f, b_hh_f, b_ih_b, b_hh_b,
                       wdyn_bf, wih_bf, whh_h, bsum, flags);
    hipLaunchKernelGGL(k_fused, dim3(256), dim3(256), 0, stream,
                       x_dynamic, wdyn_bf, b_dyn, wih_bf, bsum,
                       xw, whh_h, norder, nw, accf, accb, flags,
                       x_static, w_s1, b_s1, w_s2, b_s2, nb, statd);
    hipLaunchKernelGGL(k_final, dim3((BT + 255) / 256), dim3(256), 0, stream,
                       statd, accf, accb, out);
}